// Round 7
// baseline (167.615 us; speedup 1.0000x reference)
//
#include <hip/hip_runtime.h>
#include <stdint.h>

#define B_  16
#define C_  512
#define C1_ 256
#define HW_ 4096

using bf16x8 = __attribute__((ext_vector_type(8))) short;
using f32x4  = __attribute__((ext_vector_type(4))) float;

__device__ __forceinline__ short f2bf(float f) {
  union { float f; unsigned int u; } v; v.f = f;
  unsigned int r = v.u + 0x7fffu + ((v.u >> 16) & 1u);
  return (short)(r >> 16);
}
__device__ __forceinline__ float bf2f(short s) {
  union { unsigned int u; float f; } v;
  v.u = ((unsigned int)(unsigned short)s) << 16;
  return v.f;
}

__device__ __forceinline__ void gload_lds16(const void* g, void* l) {
  __builtin_amdgcn_global_load_lds(
      (const __attribute__((address_space(1))) void*)g,
      (__attribute__((address_space(3))) void*)l, 16, 0, 0);
}

// ---------------------------------------------------------------------------
// K1 (v5): x f32 [b][c][hw] -> Xbf bf16 [b][c][hw] AND XbfT bf16 [b][hw][c].
// Register transpose, 8c x 8n per thread, ALL 16 float4 loads in flight.
// __launch_bounds__(256, 3) lifts the VGPR cap to ~170 so the loads are NOT
// serialized by the register allocator (r6: VGPR=40 silently chunked them).
// grid: dim3(16, 8, 16), 256 threads.
__global__ __launch_bounds__(256, 3) void k_convert(const float* __restrict__ x,
                                                    short* __restrict__ Xbf,
                                                    short* __restrict__ XbfT) {
  const int n0 = blockIdx.x * 256, c0 = blockIdx.y * 64, b = blockIdx.z;
  const int t = threadIdx.x;
  const int i = t & 7;                 // c-group: rows c0 + i*8 + e
  const int j = t >> 3;                // n-group: cols n0 + j*8 .. +7
  const int cbase = c0 + i * 8;
  const int nbase = n0 + j * 8;
  float4 v[8][2];
#pragma unroll
  for (int e = 0; e < 8; ++e) {
    const float* row = x + ((size_t)(b * C_ + cbase + e)) * HW_ + nbase;
    v[e][0] = *(const float4*)(row);
    v[e][1] = *(const float4*)(row + 4);
  }
  short bf[8][8];
#pragma unroll
  for (int e = 0; e < 8; ++e) {
    bf16x8 o;
    o[0] = f2bf(v[e][0].x); o[1] = f2bf(v[e][0].y);
    o[2] = f2bf(v[e][0].z); o[3] = f2bf(v[e][0].w);
    o[4] = f2bf(v[e][1].x); o[5] = f2bf(v[e][1].y);
    o[6] = f2bf(v[e][1].z); o[7] = f2bf(v[e][1].w);
#pragma unroll
    for (int d = 0; d < 8; ++d) bf[e][d] = o[d];
    *(bf16x8*)(Xbf + ((size_t)(b * C_ + cbase + e)) * HW_ + nbase) = o;
  }
#pragma unroll
  for (int d = 0; d < 8; ++d) {
    bf16x8 o;
#pragma unroll
    for (int e = 0; e < 8; ++e) o[e] = bf[e][d];
    *(bf16x8*)(XbfT + ((size_t)b * HW_ + nbase + d) * C_ + cbase) = o;
  }
}

// ---------------------------------------------------------------------------
// K1b: conv_w f32 [256][512] -> Wbf bf16 [256][512].
__global__ __launch_bounds__(256) void k_wconv(const float* __restrict__ W,
                                               short* __restrict__ Wbf) {
  const int q = blockIdx.x, t = threadIdx.x;
  const float2 v = ((const float2*)(W + (size_t)q * C_))[t];
  short2 o; o.x = f2bf(v.x); o.y = f2bf(v.y);
  ((short2*)(Wbf + (size_t)q * C_))[t] = o;
}

// ---------------------------------------------------------------------------
// Shared NT-GEMM 128x128 mainloop, double-buffered LDS with prefetch.
// Pre-barrier drain is vmcnt(0) AND lgkmcnt(0) (race fix, rule #18/m152).
template<int KITER, int LDK>
__device__ __forceinline__ void nt_loop(const short* __restrict__ Ab,
                                        const short* __restrict__ Bb,
                                        short* As, short* Bs, int t,
                                        f32x4 (&acc)[4][4]) {
  const int lane = t & 63, w = t >> 6;
  const int wr = w >> 1, wc = w & 1;
  const int fr = lane & 15, fk = (lane >> 4) * 8;
  const int row_st = t >> 2, k_st = (t & 3) * 8;

#define STAGE_(buf, kk)                                                         \
  {                                                                             \
    const int k0_ = (kk) * 32 + k_st;                                           \
    gload_lds16(Ab + (size_t)row_st * LDK + k0_, As + (buf) * 4096 + t * 8);    \
    gload_lds16(Ab + (size_t)(row_st + 64) * LDK + k0_,                         \
                As + (buf) * 4096 + 2048 + t * 8);                              \
    gload_lds16(Bb + (size_t)row_st * LDK + k0_, Bs + (buf) * 4096 + t * 8);    \
    gload_lds16(Bb + (size_t)(row_st + 64) * LDK + k0_,                         \
                Bs + (buf) * 4096 + 2048 + t * 8);                              \
  }

  STAGE_(0, 0);
  asm volatile("s_waitcnt vmcnt(0)" ::: "memory");
  __builtin_amdgcn_s_barrier();
  int cur = 0;
  for (int kk = 0; kk < KITER; ++kk) {
    if (kk + 1 < KITER) STAGE_(cur ^ 1, kk + 1);
    const short* Ac = As + cur * 4096;
    const short* Bc = Bs + cur * 4096;
    bf16x8 a[4], bv[4];
#pragma unroll
    for (int m = 0; m < 4; ++m)
      a[m] = *(const bf16x8*)&Ac[(wr * 64 + m * 16 + fr) * 32 + fk];
#pragma unroll
    for (int n = 0; n < 4; ++n)
      bv[n] = *(const bf16x8*)&Bc[(wc * 64 + n * 16 + fr) * 32 + fk];
#pragma unroll
    for (int m = 0; m < 4; ++m)
#pragma unroll
      for (int n = 0; n < 4; ++n)
        acc[m][n] = __builtin_amdgcn_mfma_f32_16x16x32_bf16(a[m], bv[n], acc[m][n], 0, 0, 0);
    asm volatile("s_waitcnt vmcnt(0) lgkmcnt(0)" ::: "memory");
    __builtin_amdgcn_s_barrier();
    cur ^= 1;
  }
#undef STAGE_
}

// ---------------------------------------------------------------------------
// K2: Q[b][q][n] = sum_c W[q][c]*XbfT[b][n][c] + conv_b[q]  (bf16 out).
// grid: dim3(64, 16): x = nt*2+mt, y = b. 256 threads.
__global__ __launch_bounds__(256, 2) void k_q(const short* __restrict__ Wbf,
                                              const short* __restrict__ XbfT,
                                              const float* __restrict__ convb,
                                              short* __restrict__ Qbf) {
  __shared__ short As[2 * 4096];
  __shared__ short Bs[2 * 4096];
  const int t = threadIdx.x;
  const int mt = blockIdx.x & 1, nt = blockIdx.x >> 1, b = blockIdx.y;
  const short* Ab = Wbf + (size_t)(mt * 128) * C_;
  const short* Bb = XbfT + ((size_t)b * HW_ + nt * 128) * C_;
  f32x4 acc[4][4] = {};
  nt_loop<16, C_>(Ab, Bb, As, Bs, t, acc);
  const int lane = t & 63, w = t >> 6;
  const int wr = w >> 1, wc = w & 1;
  const int q_base = mt * 128 + wr * 64;
  const int n_base = nt * 128 + wc * 64;
#pragma unroll
  for (int m = 0; m < 4; ++m)
#pragma unroll
    for (int n = 0; n < 4; ++n) {
      const int q = q_base + m * 16 + (lane >> 4) * 4;
      const int nn = n_base + n * 16 + (lane & 15);
#pragma unroll
      for (int r = 0; r < 4; ++r)
        Qbf[((size_t)b * C1_ + q + r) * HW_ + nn] = f2bf(acc[m][n][r] + convb[q + r]);
    }
}

// ---------------------------------------------------------------------------
// K3: Ep[ks][b][q][c] = sum_{hw chunk ks} Q[b][q][hw]*X[b][c][hw] (bf16).
// grid: dim3(16, 8, NKS): x=b, y=ct*2+qt, z=ks. 256 threads.
template<int KITER>
__global__ __launch_bounds__(256, 2) void k_e(const short* __restrict__ Qbf,
                                              const short* __restrict__ Xbf,
                                              short* __restrict__ Ep) {
  __shared__ short As[2 * 4096];
  __shared__ short Bs[2 * 4096];
  const int t = threadIdx.x;
  const int b = blockIdx.x;
  const int qt = blockIdx.y & 1, ct = blockIdx.y >> 1;
  const int ks = blockIdx.z;
  const short* Ab = Qbf + ((size_t)b * C1_ + qt * 128) * HW_ + (size_t)ks * (KITER * 32);
  const short* Bb = Xbf + ((size_t)b * C_ + ct * 128) * HW_ + (size_t)ks * (KITER * 32);
  f32x4 acc[4][4] = {};
  nt_loop<KITER, HW_>(Ab, Bb, As, Bs, t, acc);
  const int lane = t & 63, w = t >> 6;
  const int wr = w >> 1, wc = w & 1;
  const int q_base = qt * 128 + wr * 64;
  const int c_base = ct * 128 + wc * 64;
#pragma unroll
  for (int m = 0; m < 4; ++m)
#pragma unroll
    for (int n = 0; n < 4; ++n) {
      const int q = q_base + m * 16 + (lane >> 4) * 4;
      const int c = c_base + n * 16 + (lane & 15);
#pragma unroll
      for (int r = 0; r < 4; ++r)
        Ep[(((size_t)ks * B_ + b) * C1_ + q + r) * C_ + c] = f2bf(acc[m][n][r]);
    }
}

// ---------------------------------------------------------------------------
// K4: per (b,q) row: E = (sum_ks Ep)/64; A = softmax(E); Mb = gamma*A + W[q].
// grid: 4096 blocks (b*256+q), 128 threads (4 consecutive c each).
template<int NKS>
__global__ __launch_bounds__(128) void k_softmax(const short* __restrict__ Ep,
                                                 const float* __restrict__ W,
                                                 const float* __restrict__ gamma,
                                                 short* __restrict__ Mb) {
  const int bq = blockIdx.x;
  const int b = bq >> 8, q = bq & 255;
  const int t = threadIdx.x;
  const float g = gamma[0];
  float e[4] = {0.f, 0.f, 0.f, 0.f};
#pragma unroll
  for (int ks = 0; ks < NKS; ++ks) {
    const short4 v = *(const short4*)&Ep[(((size_t)ks * B_ + b) * C1_ + q) * C_ + t * 4];
    e[0] += bf2f(v.x); e[1] += bf2f(v.y); e[2] += bf2f(v.z); e[3] += bf2f(v.w);
  }
#pragma unroll
  for (int d = 0; d < 4; ++d) e[d] *= 0.015625f;
  float mx = fmaxf(fmaxf(e[0], e[1]), fmaxf(e[2], e[3]));
#pragma unroll
  for (int off = 1; off < 64; off <<= 1) mx = fmaxf(mx, __shfl_xor(mx, off));
  __shared__ float red[2];
  if ((t & 63) == 0) red[t >> 6] = mx;
  __syncthreads();
  mx = fmaxf(red[0], red[1]);
  const float e0 = __expf(e[0] - mx), e1 = __expf(e[1] - mx);
  const float e2 = __expf(e[2] - mx), e3 = __expf(e[3] - mx);
  float sum = (e0 + e1) + (e2 + e3);
#pragma unroll
  for (int off = 1; off < 64; off <<= 1) sum += __shfl_xor(sum, off);
  __shared__ float red2[2];
  if ((t & 63) == 0) red2[t >> 6] = sum;
  __syncthreads();
  const float inv = 1.0f / (red2[0] + red2[1]);
  const float4 wv = ((const float4*)(W + (size_t)q * C_))[t];
  short4 o;
  o.x = f2bf(g * e0 * inv + wv.x);
  o.y = f2bf(g * e1 * inv + wv.y);
  o.z = f2bf(g * e2 * inv + wv.z);
  o.w = f2bf(g * e3 * inv + wv.w);
  ((short4*)(Mb + (size_t)bq * C_))[t] = o;
}

// ---------------------------------------------------------------------------
// K5: out[b][o][n] = sum_c Mb[b][o][c]*XbfT[b][n][c] + conv_b[o]  (f32).
// grid: dim3(64, 16), 256 threads.
__global__ __launch_bounds__(256, 2) void k_out(const short* __restrict__ Mb,
                                                const short* __restrict__ XbfT,
                                                const float* __restrict__ convb,
                                                float* __restrict__ out) {
  __shared__ short As[2 * 4096];
  __shared__ short Bs[2 * 4096];
  const int t = threadIdx.x;
  const int mt = blockIdx.x & 1, nt = blockIdx.x >> 1, b = blockIdx.y;
  const short* Ab = Mb + ((size_t)b * C1_ + mt * 128) * C_;
  const short* Bb = XbfT + ((size_t)b * HW_ + nt * 128) * C_;
  f32x4 acc[4][4] = {};
  nt_loop<16, C_>(Ab, Bb, As, Bs, t, acc);
  const int lane = t & 63, w = t >> 6;
  const int wr = w >> 1, wc = w & 1;
  const int o_base = mt * 128 + wr * 64;
  const int n_base = nt * 128 + wc * 64;
#pragma unroll
  for (int m = 0; m < 4; ++m)
#pragma unroll
    for (int n = 0; n < 4; ++n) {
      const int oo = o_base + m * 16 + (lane >> 4) * 4;
      const int nn = n_base + n * 16 + (lane & 15);
#pragma unroll
      for (int r = 0; r < 4; ++r)
        out[((size_t)b * C1_ + oo + r) * HW_ + nn] = acc[m][n][r] + convb[oo + r];
    }
}

// ---------------------------------------------------------------------------
extern "C" void kernel_launch(void* const* d_in, const int* in_sizes, int n_in,
                              void* d_out, int out_size, void* d_ws, size_t ws_size,
                              hipStream_t stream) {
  const float* x      = (const float*)d_in[0];
  const float* conv_w = (const float*)d_in[1];
  const float* conv_b = (const float*)d_in[2];
  const float* gamma  = (const float*)d_in[3];
  float* out = (float*)d_out;

  char* ws = (char*)d_ws;
  short* Xbf  = (short*)(ws);                 //  67,108,864 B : bf16 [16][512][4096]
  short* XbfT = (short*)(ws + 67108864);      //  67,108,864 B : bf16 [16][4096][512]
  short* Qbf  = (short*)(ws + 134217728);     //  33,554,432 B : bf16 [16][256][4096]
  short* Mb   = (short*)(ws + 134217728);     //  (aliases Qbf; Qbf dead by then)
  short* Ep   = (short*)(ws + 167772160);     //  up to 33,554,432 B (8 splits)
  const bool big = ws_size >= 201588736ull;   //  split-K 8 if Ep x8 + Wbf fit
  short* Wbf  = (short*)(ws + (big ? 201326592u : 184549376u));

  k_convert<<<dim3(16, 8, 16), 256, 0, stream>>>(x, Xbf, XbfT);
  k_wconv<<<256, 256, 0, stream>>>(conv_w, Wbf);
  k_q<<<dim3(64, 16), 256, 0, stream>>>(Wbf, XbfT, conv_b, Qbf);
  if (big) {
    k_e<16><<<dim3(16, 8, 8), 256, 0, stream>>>(Qbf, Xbf, Ep);
    k_softmax<8><<<4096, 128, 0, stream>>>(Ep, conv_w, gamma, Mb);
  } else {
    k_e<32><<<dim3(16, 8, 4), 256, 0, stream>>>(Qbf, Xbf, Ep);
    k_softmax<4><<<4096, 128, 0, stream>>>(Ep, conv_w, gamma, Mb);
  }
  k_out<<<dim3(64, 16), 256, 0, stream>>>(Mb, XbfT, conv_b, out);
}

// Round 8
// 161.033 us; speedup vs baseline: 1.0409x; 1.0409x over previous
//
#include <hip/hip_runtime.h>
#include <stdint.h>

#define B_  16
#define C_  512
#define C1_ 256
#define HW_ 4096

using bf16x8 = __attribute__((ext_vector_type(8))) short;
using f32x4  = __attribute__((ext_vector_type(4))) float;

__device__ __forceinline__ short f2bf(float f) {
  union { float f; unsigned int u; } v; v.f = f;
  unsigned int r = v.u + 0x7fffu + ((v.u >> 16) & 1u);
  return (short)(r >> 16);
}
__device__ __forceinline__ float bf2f(short s) {
  union { unsigned int u; float f; } v;
  v.u = ((unsigned int)(unsigned short)s) << 16;
  return v.f;
}

__device__ __forceinline__ void gload_lds16(const void* g, void* l) {
  __builtin_amdgcn_global_load_lds(
      (const __attribute__((address_space(1))) void*)g,
      (__attribute__((address_space(3))) void*)l, 16, 0, 0);
}

// ---------------------------------------------------------------------------
// K1 (v6): x f32 [b][c][hw] -> Xbf bf16 [b][c][hw] AND XbfT bf16 [b][hw][c].
// Register transpose, 8c x 8n per thread. MLP FORCED via inline asm: 8 asm
// statements issue all 16 global_load_dwordx4 (compiler cannot chunk volatile
// asm), single vmcnt(0) drain, sched_barrier(0) pins converts below the wait
// (rule #18). grid: dim3(16, 8, 16), 256 threads.
__global__ __launch_bounds__(256, 3) void k_convert(const float* __restrict__ x,
                                                    short* __restrict__ Xbf,
                                                    short* __restrict__ XbfT) {
  const int n0 = blockIdx.x * 256, c0 = blockIdx.y * 64, b = blockIdx.z;
  const int t = threadIdx.x;
  const int i = t & 7;                 // c-group: rows c0 + i*8 + e
  const int j = t >> 3;                // n-group: cols n0 + j*8 .. +7
  const int cbase = c0 + i * 8;
  const int nbase = n0 + j * 8;
  float4 v[8][2];
#pragma unroll
  for (int e = 0; e < 8; ++e) {
    const float* row = x + ((size_t)(b * C_ + cbase + e)) * HW_ + nbase;
    asm volatile("global_load_dwordx4 %0, %2, off\n\t"
                 "global_load_dwordx4 %1, %2, off offset:16"
                 : "=&v"(v[e][0]), "=&v"(v[e][1])
                 : "v"(row)
                 : "memory");
  }
  asm volatile("s_waitcnt vmcnt(0)" ::: "memory");
  __builtin_amdgcn_sched_barrier(0);
  short bf[8][8];
#pragma unroll
  for (int e = 0; e < 8; ++e) {
    bf16x8 o;
    o[0] = f2bf(v[e][0].x); o[1] = f2bf(v[e][0].y);
    o[2] = f2bf(v[e][0].z); o[3] = f2bf(v[e][0].w);
    o[4] = f2bf(v[e][1].x); o[5] = f2bf(v[e][1].y);
    o[6] = f2bf(v[e][1].z); o[7] = f2bf(v[e][1].w);
#pragma unroll
    for (int d = 0; d < 8; ++d) bf[e][d] = o[d];
    *(bf16x8*)(Xbf + ((size_t)(b * C_ + cbase + e)) * HW_ + nbase) = o;
  }
#pragma unroll
  for (int d = 0; d < 8; ++d) {
    bf16x8 o;
#pragma unroll
    for (int e = 0; e < 8; ++e) o[e] = bf[e][d];
    *(bf16x8*)(XbfT + ((size_t)b * HW_ + nbase + d) * C_ + cbase) = o;
  }
}

// ---------------------------------------------------------------------------
// K1b: conv_w f32 [256][512] -> Wbf bf16 [256][512].
__global__ __launch_bounds__(256) void k_wconv(const float* __restrict__ W,
                                               short* __restrict__ Wbf) {
  const int q = blockIdx.x, t = threadIdx.x;
  const float2 v = ((const float2*)(W + (size_t)q * C_))[t];
  short2 o; o.x = f2bf(v.x); o.y = f2bf(v.y);
  ((short2*)(Wbf + (size_t)q * C_))[t] = o;
}

// ---------------------------------------------------------------------------
// Shared NT-GEMM 128x128 mainloop, double-buffered LDS with prefetch.
// Pre-barrier drain is vmcnt(0) AND lgkmcnt(0) (race fix, rule #18/m152).
template<int KITER, int LDK>
__device__ __forceinline__ void nt_loop(const short* __restrict__ Ab,
                                        const short* __restrict__ Bb,
                                        short* As, short* Bs, int t,
                                        f32x4 (&acc)[4][4]) {
  const int lane = t & 63, w = t >> 6;
  const int wr = w >> 1, wc = w & 1;
  const int fr = lane & 15, fk = (lane >> 4) * 8;
  const int row_st = t >> 2, k_st = (t & 3) * 8;

#define STAGE_(buf, kk)                                                         \
  {                                                                             \
    const int k0_ = (kk) * 32 + k_st;                                           \
    gload_lds16(Ab + (size_t)row_st * LDK + k0_, As + (buf) * 4096 + t * 8);    \
    gload_lds16(Ab + (size_t)(row_st + 64) * LDK + k0_,                         \
                As + (buf) * 4096 + 2048 + t * 8);                              \
    gload_lds16(Bb + (size_t)row_st * LDK + k0_, Bs + (buf) * 4096 + t * 8);    \
    gload_lds16(Bb + (size_t)(row_st + 64) * LDK + k0_,                         \
                Bs + (buf) * 4096 + 2048 + t * 8);                              \
  }

  STAGE_(0, 0);
  asm volatile("s_waitcnt vmcnt(0)" ::: "memory");
  __builtin_amdgcn_s_barrier();
  int cur = 0;
  for (int kk = 0; kk < KITER; ++kk) {
    if (kk + 1 < KITER) STAGE_(cur ^ 1, kk + 1);
    const short* Ac = As + cur * 4096;
    const short* Bc = Bs + cur * 4096;
    bf16x8 a[4], bv[4];
#pragma unroll
    for (int m = 0; m < 4; ++m)
      a[m] = *(const bf16x8*)&Ac[(wr * 64 + m * 16 + fr) * 32 + fk];
#pragma unroll
    for (int n = 0; n < 4; ++n)
      bv[n] = *(const bf16x8*)&Bc[(wc * 64 + n * 16 + fr) * 32 + fk];
#pragma unroll
    for (int m = 0; m < 4; ++m)
#pragma unroll
      for (int n = 0; n < 4; ++n)
        acc[m][n] = __builtin_amdgcn_mfma_f32_16x16x32_bf16(a[m], bv[n], acc[m][n], 0, 0, 0);
    asm volatile("s_waitcnt vmcnt(0) lgkmcnt(0)" ::: "memory");
    __builtin_amdgcn_s_barrier();
    cur ^= 1;
  }
#undef STAGE_
}

// ---------------------------------------------------------------------------
// K2: Q[b][q][n] = sum_c W[q][c]*XbfT[b][n][c] + conv_b[q]  (bf16 out).
// grid: dim3(64, 16): x = nt*2+mt, y = b. 256 threads.
__global__ __launch_bounds__(256, 2) void k_q(const short* __restrict__ Wbf,
                                              const short* __restrict__ XbfT,
                                              const float* __restrict__ convb,
                                              short* __restrict__ Qbf) {
  __shared__ short As[2 * 4096];
  __shared__ short Bs[2 * 4096];
  const int t = threadIdx.x;
  const int mt = blockIdx.x & 1, nt = blockIdx.x >> 1, b = blockIdx.y;
  const short* Ab = Wbf + (size_t)(mt * 128) * C_;
  const short* Bb = XbfT + ((size_t)b * HW_ + nt * 128) * C_;
  f32x4 acc[4][4] = {};
  nt_loop<16, C_>(Ab, Bb, As, Bs, t, acc);
  const int lane = t & 63, w = t >> 6;
  const int wr = w >> 1, wc = w & 1;
  const int q_base = mt * 128 + wr * 64;
  const int n_base = nt * 128 + wc * 64;
#pragma unroll
  for (int m = 0; m < 4; ++m)
#pragma unroll
    for (int n = 0; n < 4; ++n) {
      const int q = q_base + m * 16 + (lane >> 4) * 4;
      const int nn = n_base + n * 16 + (lane & 15);
#pragma unroll
      for (int r = 0; r < 4; ++r)
        Qbf[((size_t)b * C1_ + q + r) * HW_ + nn] = f2bf(acc[m][n][r] + convb[q + r]);
    }
}

// ---------------------------------------------------------------------------
// K3: Ep[ks][b][q][c] = sum_{hw chunk ks} Q[b][q][hw]*X[b][c][hw] (bf16).
// grid: dim3(16, 8, NKS): x=b, y=ct*2+qt, z=ks. 256 threads.
template<int KITER>
__global__ __launch_bounds__(256, 2) void k_e(const short* __restrict__ Qbf,
                                              const short* __restrict__ Xbf,
                                              short* __restrict__ Ep) {
  __shared__ short As[2 * 4096];
  __shared__ short Bs[2 * 4096];
  const int t = threadIdx.x;
  const int b = blockIdx.x;
  const int qt = blockIdx.y & 1, ct = blockIdx.y >> 1;
  const int ks = blockIdx.z;
  const short* Ab = Qbf + ((size_t)b * C1_ + qt * 128) * HW_ + (size_t)ks * (KITER * 32);
  const short* Bb = Xbf + ((size_t)b * C_ + ct * 128) * HW_ + (size_t)ks * (KITER * 32);
  f32x4 acc[4][4] = {};
  nt_loop<KITER, HW_>(Ab, Bb, As, Bs, t, acc);
  const int lane = t & 63, w = t >> 6;
  const int wr = w >> 1, wc = w & 1;
  const int q_base = qt * 128 + wr * 64;
  const int c_base = ct * 128 + wc * 64;
#pragma unroll
  for (int m = 0; m < 4; ++m)
#pragma unroll
    for (int n = 0; n < 4; ++n) {
      const int q = q_base + m * 16 + (lane >> 4) * 4;
      const int c = c_base + n * 16 + (lane & 15);
#pragma unroll
      for (int r = 0; r < 4; ++r)
        Ep[(((size_t)ks * B_ + b) * C1_ + q + r) * C_ + c] = f2bf(acc[m][n][r]);
    }
}

// ---------------------------------------------------------------------------
// K4: per (b,q) row: E = (sum_ks Ep)/64; A = softmax(E); Mb = gamma*A + W[q].
// grid: 4096 blocks (b*256+q), 128 threads (4 consecutive c each).
template<int NKS>
__global__ __launch_bounds__(128) void k_softmax(const short* __restrict__ Ep,
                                                 const float* __restrict__ W,
                                                 const float* __restrict__ gamma,
                                                 short* __restrict__ Mb) {
  const int bq = blockIdx.x;
  const int b = bq >> 8, q = bq & 255;
  const int t = threadIdx.x;
  const float g = gamma[0];
  float e[4] = {0.f, 0.f, 0.f, 0.f};
#pragma unroll
  for (int ks = 0; ks < NKS; ++ks) {
    const short4 v = *(const short4*)&Ep[(((size_t)ks * B_ + b) * C1_ + q) * C_ + t * 4];
    e[0] += bf2f(v.x); e[1] += bf2f(v.y); e[2] += bf2f(v.z); e[3] += bf2f(v.w);
  }
#pragma unroll
  for (int d = 0; d < 4; ++d) e[d] *= 0.015625f;
  float mx = fmaxf(fmaxf(e[0], e[1]), fmaxf(e[2], e[3]));
#pragma unroll
  for (int off = 1; off < 64; off <<= 1) mx = fmaxf(mx, __shfl_xor(mx, off));
  __shared__ float red[2];
  if ((t & 63) == 0) red[t >> 6] = mx;
  __syncthreads();
  mx = fmaxf(red[0], red[1]);
  const float e0 = __expf(e[0] - mx), e1 = __expf(e[1] - mx);
  const float e2 = __expf(e[2] - mx), e3 = __expf(e[3] - mx);
  float sum = (e0 + e1) + (e2 + e3);
#pragma unroll
  for (int off = 1; off < 64; off <<= 1) sum += __shfl_xor(sum, off);
  __shared__ float red2[2];
  if ((t & 63) == 0) red2[t >> 6] = sum;
  __syncthreads();
  const float inv = 1.0f / (red2[0] + red2[1]);
  const float4 wv = ((const float4*)(W + (size_t)q * C_))[t];
  short4 o;
  o.x = f2bf(g * e0 * inv + wv.x);
  o.y = f2bf(g * e1 * inv + wv.y);
  o.z = f2bf(g * e2 * inv + wv.z);
  o.w = f2bf(g * e3 * inv + wv.w);
  ((short4*)(Mb + (size_t)bq * C_))[t] = o;
}

// ---------------------------------------------------------------------------
// K5: out[b][o][n] = sum_c Mb[b][o][c]*XbfT[b][n][c] + conv_b[o]  (f32).
// grid: dim3(64, 16), 256 threads.
__global__ __launch_bounds__(256, 2) void k_out(const short* __restrict__ Mb,
                                                const short* __restrict__ XbfT,
                                                const float* __restrict__ convb,
                                                float* __restrict__ out) {
  __shared__ short As[2 * 4096];
  __shared__ short Bs[2 * 4096];
  const int t = threadIdx.x;
  const int mt = blockIdx.x & 1, nt = blockIdx.x >> 1, b = blockIdx.y;
  const short* Ab = Mb + ((size_t)b * C1_ + mt * 128) * C_;
  const short* Bb = XbfT + ((size_t)b * HW_ + nt * 128) * C_;
  f32x4 acc[4][4] = {};
  nt_loop<16, C_>(Ab, Bb, As, Bs, t, acc);
  const int lane = t & 63, w = t >> 6;
  const int wr = w >> 1, wc = w & 1;
  const int o_base = mt * 128 + wr * 64;
  const int n_base = nt * 128 + wc * 64;
#pragma unroll
  for (int m = 0; m < 4; ++m)
#pragma unroll
    for (int n = 0; n < 4; ++n) {
      const int oo = o_base + m * 16 + (lane >> 4) * 4;
      const int nn = n_base + n * 16 + (lane & 15);
#pragma unroll
      for (int r = 0; r < 4; ++r)
        out[((size_t)b * C1_ + oo + r) * HW_ + nn] = acc[m][n][r] + convb[oo + r];
    }
}

// ---------------------------------------------------------------------------
extern "C" void kernel_launch(void* const* d_in, const int* in_sizes, int n_in,
                              void* d_out, int out_size, void* d_ws, size_t ws_size,
                              hipStream_t stream) {
  const float* x      = (const float*)d_in[0];
  const float* conv_w = (const float*)d_in[1];
  const float* conv_b = (const float*)d_in[2];
  const float* gamma  = (const float*)d_in[3];
  float* out = (float*)d_out;

  char* ws = (char*)d_ws;
  short* Xbf  = (short*)(ws);                 //  67,108,864 B : bf16 [16][512][4096]
  short* XbfT = (short*)(ws + 67108864);      //  67,108,864 B : bf16 [16][4096][512]
  short* Qbf  = (short*)(ws + 134217728);     //  33,554,432 B : bf16 [16][256][4096]
  short* Mb   = (short*)(ws + 134217728);     //  (aliases Qbf; Qbf dead by then)
  short* Ep   = (short*)(ws + 167772160);     //  up to 33,554,432 B (8 splits)
  const bool big = ws_size >= 201588736ull;   //  split-K 8 if Ep x8 + Wbf fit
  short* Wbf  = (short*)(ws + (big ? 201326592u : 184549376u));

  k_convert<<<dim3(16, 8, 16), 256, 0, stream>>>(x, Xbf, XbfT);
  k_wconv<<<256, 256, 0, stream>>>(conv_w, Wbf);
  k_q<<<dim3(64, 16), 256, 0, stream>>>(Wbf, XbfT, conv_b, Qbf);
  if (big) {
    k_e<16><<<dim3(16, 8, 8), 256, 0, stream>>>(Qbf, Xbf, Ep);
    k_softmax<8><<<4096, 128, 0, stream>>>(Ep, conv_w, gamma, Mb);
  } else {
    k_e<32><<<dim3(16, 8, 4), 256, 0, stream>>>(Qbf, Xbf, Ep);
    k_softmax<4><<<4096, 128, 0, stream>>>(Ep, conv_w, gamma, Mb);
  }
  k_out<<<dim3(64, 16), 256, 0, stream>>>(Mb, XbfT, conv_b, out);
}